// Round 9
// baseline (251.871 us; speedup 1.0000x reference)
//
#include <hip/hip_runtime.h>

// out[n,0,p,Y,Z] = sum_k y[n,k,0,Y/4,Z/4] * W[k,0,p,Y%4,Z%4]
// y: (8,128,1,16,16)  W: (128,1,1024,4,4)  out: (8,1,1024,64,64)
//
// R9: uniform distance-2 pipeline. R8 showed VALUBusy stuck at 54%:
// wB had only 128 FMA-cycles of cover and y ds_reads sat on the
// loop-carried path. Now: 4-k loop, named A/B buffers, every load
// (global W and LDS y) issued one full 128-FMA block before use.
// launch_bounds(256,3): 170-reg cap fits ~155 live regs w/o spill;
// occupancy was 3 waves/SIMD anyway.

#define Y_N_STRIDE   32768     // 128*16*16
#define W_K_STRIDE   16384     // 1024*4*4
#define OUT_N_STRIDE 4194304   // 1024*64*64

#define FMA_ROW(ys, wv, i)                                   \
    _Pragma("unroll")                                        \
    for (int j = 0; j < 4; ++j) {                            \
        acc[i][j][0] = fmaf(ys, wv[j].x, acc[i][j][0]);      \
        acc[i][j][1] = fmaf(ys, wv[j].y, acc[i][j][1]);      \
        acc[i][j][2] = fmaf(ys, wv[j].z, acc[i][j][2]);      \
        acc[i][j][3] = fmaf(ys, wv[j].w, acc[i][j][3]);      \
    }

#define FMA_K(yv, wv)            \
    FMA_ROW(yv.x, wv, 0)         \
    FMA_ROW(yv.y, wv, 1)         \
    FMA_ROW(yv.z, wv, 2)         \
    FMA_ROW(yv.w, wv, 3)

__global__ __launch_bounds__(256, 3)
void backproj_kernel(const float* __restrict__ y,
                     const float* __restrict__ W,
                     float* __restrict__ out) {
    // y_s[k][z][i] : y[n, k, yy0+i, z] at y_s[k*64 + z*4 + i]  (32 KiB)
    __shared__ float y_s[128 * 64];

    const int tid  = threadIdx.x;
    const int lane = tid & 63;
    const int zz   = lane & 15;       // z-block index (16)
    const int q    = (lane >> 4) & 3; // b2 index (4)
    const int wave = tid >> 6;        // 0..3

    const int bid = blockIdx.x;
    const int pc  = bid & 63;         // p chunk (64 chunks of 16)
    const int yyg = (bid >> 6) & 3;   // yy group (4 groups of 4)
    const int n   = bid >> 8;         // batch (8)

    const int p0  = pc * 16 + wave * 4;  // this thread's 4 p values
    const int yy0 = yyg * 4;             // this thread's 4 yy values

    // W[k, p0+j, q, 0..3] = Wb[k*16384 + j*16 .. +3]
    const float* Wb = W + p0 * 16 + q * 4;

    // ---- prologue W loads (k=0,1) issued BEFORE staging: covered by it ----
    float4 wA0[4], wA1[4], wB0[4], wB1[4];
    #pragma unroll
    for (int j = 0; j < 4; ++j) {
        wA0[j] = *reinterpret_cast<const float4*>(Wb + 0 * W_K_STRIDE + j * 16);
        wA1[j] = *reinterpret_cast<const float4*>(Wb + 1 * W_K_STRIDE + j * 16);
    }

    // ---- stage y into LDS with [i][z] -> [z][i] transpose ----
    {
        const float* yb = y + n * Y_N_STRIDE + yy0 * 16;
        #pragma unroll
        for (int r = 0; r < 8; ++r) {
            const int f  = tid + r * 256;   // float4 index in [0,2048)
            const int k  = f >> 4;          // 16 float4 per k-row
            const int li = (f & 15) * 4;    // = i*16 + z0 within the k-row
            const int i  = li >> 4;
            const int z0 = li & 15;
            float4 v = *reinterpret_cast<const float4*>(yb + k * 256 + li);
            float* dst = &y_s[k * 64 + z0 * 4 + i];
            dst[0]  = v.x;
            dst[4]  = v.y;
            dst[8]  = v.z;
            dst[12] = v.w;
        }
    }
    __syncthreads();

    float4 yA0 = *reinterpret_cast<const float4*>(&y_s[0 * 64 + zz * 4]);
    float4 yA1 = *reinterpret_cast<const float4*>(&y_s[1 * 64 + zz * 4]);
    float4 yB0, yB1;

    float acc[4][4][4]; // [yy][p][r]
    #pragma unroll
    for (int i = 0; i < 4; ++i)
        #pragma unroll
        for (int j = 0; j < 4; ++j)
            #pragma unroll
            for (int r = 0; r < 4; ++r)
                acc[i][j][r] = 0.0f;

    #pragma unroll 1
    for (int k = 0; k < 128; k += 4) {
        // prefetch (k+2, k+3) into B — consumed after 128 FMAs below
        #pragma unroll
        for (int j = 0; j < 4; ++j) {
            wB0[j] = *reinterpret_cast<const float4*>(
                         Wb + (k + 2) * W_K_STRIDE + j * 16);
            wB1[j] = *reinterpret_cast<const float4*>(
                         Wb + (k + 3) * W_K_STRIDE + j * 16);
        }
        yB0 = *reinterpret_cast<const float4*>(&y_s[(k + 2) * 64 + zz * 4]);
        yB1 = *reinterpret_cast<const float4*>(&y_s[(k + 3) * 64 + zz * 4]);

        FMA_K(yA0, wA0)
        FMA_K(yA1, wA1)

        // prefetch (k+4, k+5) into A — consumed after 128 FMAs below
        if (k + 4 < 128) {
            #pragma unroll
            for (int j = 0; j < 4; ++j) {
                wA0[j] = *reinterpret_cast<const float4*>(
                             Wb + (k + 4) * W_K_STRIDE + j * 16);
                wA1[j] = *reinterpret_cast<const float4*>(
                             Wb + (k + 5) * W_K_STRIDE + j * 16);
            }
            yA0 = *reinterpret_cast<const float4*>(&y_s[(k + 4) * 64 + zz * 4]);
            yA1 = *reinterpret_cast<const float4*>(&y_s[(k + 5) * 64 + zz * 4]);
        }

        FMA_K(yB0, wB0)
        FMA_K(yB1, wB1)
    }

    // out[n, p0+j, (yy0+i)*4+q, zz*4 + 0..3] — 1 KiB contiguous per wave instr
    float* ob = out + (size_t)n * OUT_N_STRIDE + zz * 4;
    #pragma unroll
    for (int i = 0; i < 4; ++i) {
        const int Y = (yy0 + i) * 4 + q;
        #pragma unroll
        for (int j = 0; j < 4; ++j) {
            float4 v = make_float4(acc[i][j][0], acc[i][j][1],
                                   acc[i][j][2], acc[i][j][3]);
            *reinterpret_cast<float4*>(ob + (p0 + j) * 4096 + Y * 64) = v;
        }
    }
}

extern "C" void kernel_launch(void* const* d_in, const int* in_sizes, int n_in,
                              void* d_out, int out_size, void* d_ws, size_t ws_size,
                              hipStream_t stream) {
    const float* y = (const float*)d_in[0];
    const float* W = (const float*)d_in[1];
    float* out = (float*)d_out;

    // grid: 8 n * 4 yy-groups * 64 p-chunks
    dim3 grid(2048);
    dim3 block(256);
    backproj_kernel<<<grid, block, 0, stream>>>(y, W, out);
}

// Round 10
// 248.324 us; speedup vs baseline: 1.0143x; 1.0143x over previous
//
#include <hip/hip_runtime.h>

// out[n,0,p,Y,Z] = sum_k y[n,k,0,Y/4,Z/4] * W[k,0,p,Y%4,Z%4]
// y: (8,128,1,16,16)  W: (128,1,1024,4,4)  out: (8,1,1024,64,64)
//
// R10: packed-FMA. R4/R8/R9 all pinned at VALU-issue ~85us ~= 8.6 GFLOP /
// 103 TF = the practical SCALAR v_fma_f32 ceiling. MI355X's 157.3 TF fp32
// is the PACKED (v_pk_fma_f32) rate. Pair the r-axis (W float4 halves are
// natural VGPR pairs), broadcast y per i: 32 pk_fma per k instead of 64 fma.
// Inline asm guarantees v_pk_fma_f32 selection; bit-exact same accumulation.

typedef float v2f __attribute__((ext_vector_type(2)));

#define Y_N_STRIDE   32768     // 128*16*16
#define W_K_STRIDE   16384     // 1024*4*4
#define OUT_N_STRIDE 4194304   // 1024*64*64

// D = S0*S1 + D  (per 32-bit half of the 64-bit pair)
#define PK_FMA(acc, y2, w2) \
    asm("v_pk_fma_f32 %0, %1, %2, %0" : "+v"(acc) : "v"(y2), "v"(w2))

// one k-step: yv (float4 = y_i, i=0..3), wv (float4[4] = W[j].r)
#define PK_BLOCK(yv, wv)                                                  \
    {                                                                     \
        v2f y2_0 = {yv.x, yv.x}, y2_1 = {yv.y, yv.y};                     \
        v2f y2_2 = {yv.z, yv.z}, y2_3 = {yv.w, yv.w};                     \
        _Pragma("unroll")                                                 \
        for (int j = 0; j < 4; ++j) {                                     \
            const v2f* wp = reinterpret_cast<const v2f*>(&wv[j]);         \
            PK_FMA(acc2[0][j][0], y2_0, wp[0]);                           \
            PK_FMA(acc2[0][j][1], y2_0, wp[1]);                           \
            PK_FMA(acc2[1][j][0], y2_1, wp[0]);                           \
            PK_FMA(acc2[1][j][1], y2_1, wp[1]);                           \
            PK_FMA(acc2[2][j][0], y2_2, wp[0]);                           \
            PK_FMA(acc2[2][j][1], y2_2, wp[1]);                           \
            PK_FMA(acc2[3][j][0], y2_3, wp[0]);                           \
            PK_FMA(acc2[3][j][1], y2_3, wp[1]);                           \
        }                                                                 \
    }

__global__ __launch_bounds__(256, 3)
void backproj_kernel(const float* __restrict__ y,
                     const float* __restrict__ W,
                     float* __restrict__ out) {
    // y_s[k][z][i] : y[n, k, yy0+i, z] at y_s[k*64 + z*4 + i]  (32 KiB)
    __shared__ float y_s[128 * 64];

    const int tid  = threadIdx.x;
    const int lane = tid & 63;
    const int zz   = lane & 15;       // z-block index (16)
    const int q    = (lane >> 4) & 3; // b2 index (4)
    const int wave = tid >> 6;        // 0..3

    const int bid = blockIdx.x;
    const int pc  = bid & 63;         // p chunk (64 chunks of 16)
    const int yyg = (bid >> 6) & 3;   // yy group (4 groups of 4)
    const int n   = bid >> 8;         // batch (8)

    const int p0  = pc * 16 + wave * 4;  // this thread's 4 p values
    const int yy0 = yyg * 4;             // this thread's 4 yy values

    // W[k, p0+j, q, 0..3] = Wb[k*16384 + j*16 .. +3]
    const float* Wb = W + p0 * 16 + q * 4;

    // prologue W load (k=0) issued BEFORE staging: covered by it
    float4 wA[4], wB[4];
    #pragma unroll
    for (int j = 0; j < 4; ++j)
        wA[j] = *reinterpret_cast<const float4*>(Wb + j * 16);

    // ---- stage y into LDS with [i][z] -> [z][i] transpose ----
    {
        const float* yb = y + n * Y_N_STRIDE + yy0 * 16;
        #pragma unroll
        for (int r = 0; r < 8; ++r) {
            const int f  = tid + r * 256;   // float4 index in [0,2048)
            const int k  = f >> 4;          // 16 float4 per k-row
            const int li = (f & 15) * 4;    // = i*16 + z0 within the k-row
            const int i  = li >> 4;
            const int z0 = li & 15;
            float4 v = *reinterpret_cast<const float4*>(yb + k * 256 + li);
            float* dst = &y_s[k * 64 + z0 * 4 + i];
            dst[0]  = v.x;
            dst[4]  = v.y;
            dst[8]  = v.z;
            dst[12] = v.w;
        }
    }
    __syncthreads();

    v2f acc2[4][4][2]; // [yy][p][r-pair]
    #pragma unroll
    for (int i = 0; i < 4; ++i)
        #pragma unroll
        for (int j = 0; j < 4; ++j)
            #pragma unroll
            for (int h = 0; h < 2; ++h)
                acc2[i][j][h] = 0.0f;

    #pragma unroll 1
    for (int k = 0; k < 128; k += 2) {
        // issue W(k+1) into B; flies under pk-FMA block A
        #pragma unroll
        for (int j = 0; j < 4; ++j)
            wB[j] = *reinterpret_cast<const float4*>(
                        Wb + (k + 1) * W_K_STRIDE + j * 16);

        // both y reads issued early (immediate-offset ds_read_b128)
        float4 yv0 = *reinterpret_cast<const float4*>(&y_s[k * 64 + zz * 4]);
        float4 yv1 = *reinterpret_cast<const float4*>(&y_s[(k + 1) * 64 + zz * 4]);

        PK_BLOCK(yv0, wA)

        // issue W(k+2) into A (A dead now); flies under pk-FMA block B
        if (k + 2 < 128) {
            #pragma unroll
            for (int j = 0; j < 4; ++j)
                wA[j] = *reinterpret_cast<const float4*>(
                            Wb + (k + 2) * W_K_STRIDE + j * 16);
        }

        PK_BLOCK(yv1, wB)
    }

    // out[n, p0+j, (yy0+i)*4+q, zz*4 + 0..3] — 1 KiB contiguous per wave instr
    float* ob = out + (size_t)n * OUT_N_STRIDE + zz * 4;
    #pragma unroll
    for (int i = 0; i < 4; ++i) {
        const int Y = (yy0 + i) * 4 + q;
        #pragma unroll
        for (int j = 0; j < 4; ++j) {
            float4 v;
            v.x = acc2[i][j][0].x;
            v.y = acc2[i][j][0].y;
            v.z = acc2[i][j][1].x;
            v.w = acc2[i][j][1].y;
            *reinterpret_cast<float4*>(ob + (p0 + j) * 4096 + Y * 64) = v;
        }
    }
}

extern "C" void kernel_launch(void* const* d_in, const int* in_sizes, int n_in,
                              void* d_out, int out_size, void* d_ws, size_t ws_size,
                              hipStream_t stream) {
    const float* y = (const float*)d_in[0];
    const float* W = (const float*)d_in[1];
    float* out = (float*)d_out;

    // grid: 8 n * 4 yy-groups * 64 p-chunks
    dim3 grid(2048);
    dim3 block(256);
    backproj_kernel<<<grid, block, 0, stream>>>(y, W, out);
}